// Round 9
// baseline (236.087 us; speedup 1.0000x reference)
//
#include <hip/hip_runtime.h>

typedef unsigned short u16;
typedef unsigned int u32;
typedef __bf16 bf16x4 __attribute__((ext_vector_type(4)));
typedef __bf16 bf16x8 __attribute__((ext_vector_type(8)));
typedef float f32x4 __attribute__((ext_vector_type(4)));
typedef u32 u32x4 __attribute__((ext_vector_type(4)));

struct __align__(4) U16x2 { u16 x, y; };
struct __align__(8) U16x4 { u16 x, y, z, w; };

#define DEV static __device__ __forceinline__

extern "C" __device__ float __ocml_exp2_f32(float);
#if __has_builtin(__builtin_amdgcn_exp2f)
#define EXP2(x) __builtin_amdgcn_exp2f(x)
#else
#define EXP2(x) __ocml_exp2_f32(x)
#endif

DEV u16 f2bf(float f) {
  __bf16 h = (__bf16)f;
  return __builtin_bit_cast(u16, h);
}
DEV u32 pk2bf(float lo, float hi) { return (u32)f2bf(lo) | ((u32)f2bf(hi) << 16); }

DEV void gload16(const void* g, void* l) {
  __builtin_amdgcn_global_load_lds((const __attribute__((address_space(1))) char*)g,
                                   (__attribute__((address_space(3))) char*)l, 16, 0, 0);
}

DEV f32x4 mfma16(bf16x8 a, bf16x8 b, f32x4 c) {
  return __builtin_amdgcn_mfma_f32_16x16x32_bf16(a, b, c, 0, 0, 0);
}

// ---------------------------------------------------------------------------
// x fp32 -> bf16, 4 elems/thread
__global__ __launch_bounds__(256) void cvt_x(const float* __restrict__ x, u16* __restrict__ xb) {
  int i = blockIdx.x * 256 + threadIdx.x;
  float4 v = ((const float4*)x)[i];
  U16x4 o;
  o.x = f2bf(v.x); o.y = f2bf(v.y); o.z = f2bf(v.z); o.w = f2bf(v.w);
  ((U16x4*)xb)[i] = o;
}

// ---------------------------------------------------------------------------
// fp32 [R][C] -> bf16 dst[nOff + c][r] (transposed), ldd = R
__global__ __launch_bounds__(256) void tconv(const float* __restrict__ src, u16* __restrict__ dst,
                                             int C, int nOff, int ldd) {
  __shared__ float t[32][33];
  int bx = blockIdx.x, by = blockIdx.y;
  int tx = threadIdx.x, ty = threadIdx.y;
#pragma unroll
  for (int j = 0; j < 4; ++j)
    t[ty + 8 * j][tx] = src[(size_t)(by * 32 + ty + 8 * j) * C + bx * 32 + tx];
  __syncthreads();
#pragma unroll
  for (int j = 0; j < 4; ++j)
    dst[(size_t)(nOff + bx * 32 + ty + 8 * j) * ldd + by * 32 + tx] = f2bf(t[tx][ty + 8 * j]);
}

// ---------------------------------------------------------------------------
// bf16 V-slice [4096][512] -> Vt[(b*8+kh)*64+d][s]  (plain transpose)
__global__ __launch_bounds__(256) void vtrans(const u16* __restrict__ Vsl, u16* __restrict__ Vt) {
  __shared__ u16 t[32][33];
  int bx = blockIdx.x, by = blockIdx.y, bz = blockIdx.z;
  int tx = threadIdx.x, ty = threadIdx.y;
  int b = bz >> 3, kh = bz & 7;
  const u16* src = Vsl + (size_t)(b * 2048 + bx * 32) * 512 + kh * 64 + by * 32;
#pragma unroll
  for (int j = 0; j < 4; ++j) t[ty + 8 * j][tx] = src[(size_t)(ty + 8 * j) * 512 + tx];
  __syncthreads();
  u16* dst = Vt + ((size_t)bz * 64 + by * 32) * 2048 + bx * 32;
#pragma unroll
  for (int j = 0; j < 4; ++j) dst[(size_t)(ty + 8 * j) * 2048 + tx] = t[tx][ty + 8 * j];
}

// ---------------------------------------------------------------------------
// QKV GEMM with fused RoPE epilogue. C = A[4096][2048] * BT[3072][2048]^T.
// Epilogue routes: col<2048 -> Q (roped, pre-scaled 0.125*log2e), col<2560 ->
// K (roped), else -> compact V-slice [4096][512]. RoPE pair (d even, d odd)
// lives in adjacent lanes of the C fragment -> one __shfl_xor(v,1).
__global__ __launch_bounds__(256, 2) void gemm_qkv(const u16* __restrict__ A,
                                                   const u16* __restrict__ BT,
                                                   const float* __restrict__ fc,
                                                   const float* __restrict__ fs,
                                                   u16* __restrict__ Qo,
                                                   u16* __restrict__ Ko,
                                                   u16* __restrict__ Vsl) {
  __shared__ __align__(16) char smem[65536];
  const int tid = threadIdx.x;
  const int lane = tid & 63;
  const int wm = (tid >> 7) & 1, wn = (tid >> 6) & 1;
  const int tm = blockIdx.y, tn = blockIdx.x;
  const int K = 2048, Kb = 4096, N = 3072;

  f32x4 acc[4][4];
#pragma unroll
  for (int i = 0; i < 4; ++i)
#pragma unroll
    for (int j = 0; j < 4; ++j) acc[i][j] = (f32x4){0.f, 0.f, 0.f, 0.f};

  const char* Ag = (const char*)A + (size_t)tm * 128 * Kb;
  const char* Bg = (const char*)BT + (size_t)tn * 128 * Kb;

  auto stage = [&](int buf, int t) {
#pragma unroll
    for (int i = 0; i < 4; ++i) {
      int vt = i * 256 + tid;
      int row = vt >> 3;
      int cb = (((vt & 7) << 4) ^ ((row & 7) << 4));
      gload16(Ag + (size_t)row * Kb + t * 128 + cb, smem + buf * 16384 + vt * 16);
      gload16(Bg + (size_t)row * Kb + t * 128 + cb, smem + 32768 + buf * 16384 + vt * 16);
    }
  };

  stage(0, 0);
  int cur = 0;
  const int NT = K >> 6;
  for (int t = 0; t < NT; ++t) {
    __syncthreads();
    if (t + 1 < NT) stage(cur ^ 1, t + 1);
    const char* As = smem + cur * 16384;
    const char* Bs = smem + 32768 + cur * 16384;
#pragma unroll
    for (int ks = 0; ks < 2; ++ks) {
      bf16x8 a[4], b[4];
#pragma unroll
      for (int mf = 0; mf < 4; ++mf) {
        int row = wm * 64 + mf * 16 + (lane & 15);
        int cb = (ks * 64 + ((lane >> 4) << 4)) ^ ((row & 7) << 4);
        a[mf] = *(const bf16x8*)(As + row * 128 + cb);
      }
#pragma unroll
      for (int nf = 0; nf < 4; ++nf) {
        int row = wn * 64 + nf * 16 + (lane & 15);
        int cb = (ks * 64 + ((lane >> 4) << 4)) ^ ((row & 7) << 4);
        b[nf] = *(const bf16x8*)(Bs + row * 128 + cb);
      }
#pragma unroll
      for (int mf = 0; mf < 4; ++mf)
#pragma unroll
        for (int nf = 0; nf < 4; ++nf) acc[mf][nf] = mfma16(a[mf], b[nf], acc[mf][nf]);
    }
    cur ^= 1;
  }

  const float QS = 0.18033688011112042f;  // 0.125 * log2(e)
#pragma unroll
  for (int mf = 0; mf < 4; ++mf) {
    int row0 = tm * 128 + wm * 64 + mf * 16 + ((lane >> 4) << 2);
#pragma unroll
    for (int nf = 0; nf < 4; ++nf) {
      int col = tn * 128 + wn * 64 + nf * 16 + (lane & 15);
      if (col < 2560) {  // Q or K: apply RoPE
        int d = col & 63, d2 = d >> 1;
        bool ev = !(col & 1);
        bool isQ = (col < 2048);
        int hh = isQ ? (col >> 6) : ((col - 2048) >> 6);
#pragma unroll
        for (int r = 0; r < 4; ++r) {
          int row = row0 + r;
          int bb = row >> 11, s = row & 2047;
          float v = acc[mf][nf][r];
          float p = __shfl_xor(v, 1, 64);
          float c = fc[s * 32 + d2], sn = fs[s * 32 + d2];
          if (isQ) { c *= QS; sn *= QS; }
          float o = ev ? (v * c - p * sn) : (v * c + p * sn);
          if (isQ)
            Qo[((size_t)(bb * 32 + hh) * 2048 + s) * 64 + d] = f2bf(o);
          else
            Ko[((size_t)(bb * 8 + hh) * 2048 + s) * 64 + d] = f2bf(o);
        }
      } else {  // V slice, plain
#pragma unroll
        for (int r = 0; r < 4; ++r)
          Vsl[(size_t)(row0 + r) * 512 + (col - 2560)] = f2bf(acc[mf][nf][r]);
      }
    }
  }
}

// ---------------------------------------------------------------------------
// C[M][N] = A[M][K] * BT[N][K]^T  (bf16 in, float out) -- WO GEMM, unchanged.
__global__ __launch_bounds__(256, 2) void gemm_bt(const u16* __restrict__ A,
                                                  const u16* __restrict__ BT,
                                                  float* __restrict__ C,
                                                  int M, int N, int K) {
  __shared__ __align__(16) char smem[65536];
  const int tid = threadIdx.x;
  const int lane = tid & 63;
  const int wm = (tid >> 7) & 1, wn = (tid >> 6) & 1;
  const int tm = blockIdx.y, tn = blockIdx.x;
  const int Kb = K * 2;

  f32x4 acc[4][4];
#pragma unroll
  for (int i = 0; i < 4; ++i)
#pragma unroll
    for (int j = 0; j < 4; ++j) acc[i][j] = (f32x4){0.f, 0.f, 0.f, 0.f};

  const char* Ag = (const char*)A + (size_t)tm * 128 * Kb;
  const char* Bg = (const char*)BT + (size_t)tn * 128 * Kb;

  auto stage = [&](int buf, int t) {
#pragma unroll
    for (int i = 0; i < 4; ++i) {
      int vt = i * 256 + tid;
      int row = vt >> 3;
      int cb = (((vt & 7) << 4) ^ ((row & 7) << 4));
      gload16(Ag + (size_t)row * Kb + t * 128 + cb, smem + buf * 16384 + vt * 16);
      gload16(Bg + (size_t)row * Kb + t * 128 + cb, smem + 32768 + buf * 16384 + vt * 16);
    }
  };

  stage(0, 0);
  int cur = 0;
  const int NT = K >> 6;
  for (int t = 0; t < NT; ++t) {
    __syncthreads();
    if (t + 1 < NT) stage(cur ^ 1, t + 1);
    const char* As = smem + cur * 16384;
    const char* Bs = smem + 32768 + cur * 16384;
#pragma unroll
    for (int ks = 0; ks < 2; ++ks) {
      bf16x8 a[4], b[4];
#pragma unroll
      for (int mf = 0; mf < 4; ++mf) {
        int row = wm * 64 + mf * 16 + (lane & 15);
        int cb = (ks * 64 + ((lane >> 4) << 4)) ^ ((row & 7) << 4);
        a[mf] = *(const bf16x8*)(As + row * 128 + cb);
      }
#pragma unroll
      for (int nf = 0; nf < 4; ++nf) {
        int row = wn * 64 + nf * 16 + (lane & 15);
        int cb = (ks * 64 + ((lane >> 4) << 4)) ^ ((row & 7) << 4);
        b[nf] = *(const bf16x8*)(Bs + row * 128 + cb);
      }
#pragma unroll
      for (int mf = 0; mf < 4; ++mf)
#pragma unroll
        for (int nf = 0; nf < 4; ++nf) acc[mf][nf] = mfma16(a[mf], b[nf], acc[mf][nf]);
    }
    cur ^= 1;
  }
#pragma unroll
  for (int mf = 0; mf < 4; ++mf) {
    int row0 = tm * 128 + wm * 64 + mf * 16 + ((lane >> 4) << 2);
#pragma unroll
    for (int nf = 0; nf < 4; ++nf) {
      int col = tn * 128 + wn * 64 + nf * 16 + (lane & 15);
#pragma unroll
      for (int r = 0; r < 4; ++r)
        C[(size_t)(row0 + r) * N + col] = acc[mf][nf][r];
    }
  }
}

// ---------------------------------------------------------------------------
// Causal GQA flash attention: QBLK=64 (4 waves x 16 q-rows), KVBLK=64,
// swapped QK^T, in-register P, K=32 PV via kv-permuted K staging.
// Block = (bx, h, b); qb = 31-bx (LPT: heavy first, HW backfills short ones).
// Per iteration: 64 kv rows as two 32-row subs sharing one barrier/stage and
// one combined softmax. Diagonal masks exactly one sub per wave.
__global__ __launch_bounds__(256, 4) void attn(const u16* __restrict__ Q,
                                               const u16* __restrict__ Kt,
                                               const u16* __restrict__ Vt,
                                               u16* __restrict__ O) {
  __shared__ __align__(16) char smem[32768];  // K dbuf [0,16K), V dbuf [16K,32K)

  const int tid = threadIdx.x, lane = tid & 63, w = tid >> 6;  // w in 0..3
  const int q15 = lane & 15, g = lane >> 4;
  const int qb = 31 - blockIdx.x;
  const int h = blockIdx.y, b = blockIdx.z;
  const int kh = h >> 2;

  const char* Qg = (const char*)(Q + (((size_t)(b * 32 + h) * 2048 + qb * 64) * 64));
  const char* Kg = (const char*)(Kt + ((size_t)(b * 8 + kh) * 2048 * 64));
  const char* Vg = (const char*)(Vt + ((size_t)(b * 8 + kh) * 64 * 2048));

  // Q fragments (B-operand): wave's 16 q-rows
  bf16x8 qf[2];
#pragma unroll
  for (int ks = 0; ks < 2; ++ks)
    qf[ks] = *(const bf16x8*)(Qg + (w * 16 + q15) * 128 + ks * 64 + (g << 4));

  f32x4 acc[4];
#pragma unroll
  for (int j = 0; j < 4; ++j) acc[j] = (f32x4){0.f, 0.f, 0.f, 0.f};
  float m_r = -1e30f, l_r = 0.f;
  const f32x4 FZ = (f32x4){0.f, 0.f, 0.f, 0.f};

  auto stageKV = [&](int buf, int kt) {
#pragma unroll
    for (int i = 0; i < 2; ++i) {
      int vt = i * 256 + tid;  // 0..511
      // K: LDS row rho (0..63) holds global kv = kt*64 + sub*32 + perm(rho&31)
      int rho = vt >> 3, ck = vt & 7;
      int kap = ((rho & 12) << 1) + ((rho & 16) >> 2) + (rho & 3) + ((rho >> 5) << 5);
      gload16(Kg + (size_t)(kt * 64 + kap) * 128 + (((ck ^ rho) & 7) << 4),
              smem + buf * 8192 + vt * 16);
      // V: 64 d-rows x 128B (64 kv), chunk swizzle ^(d&7)
      int d = vt >> 3, cv = vt & 7;
      gload16(Vg + (size_t)d * 4096 + kt * 128 + (((cv ^ d) & 7) << 4),
              smem + 16384 + buf * 8192 + vt * 16);
    }
  };

  stageKV(0, 0);
  int cur = 0;
  const int nkt = qb + 1;
  for (int kt = 0; kt < nkt; ++kt) {
    __syncthreads();  // KV[cur] staged (compiler drains vmcnt before barrier)
    if (kt + 1 < nkt) stageKV(cur ^ 1, kt + 1);
    const char* Ks = smem + cur * 8192;
    const char* Vs = smem + 16384 + cur * 8192;
    const bool diag = (kt == qb);
    const bool a1 = !(diag && w < 2);  // sub1 contributes nothing for waves 0,1 at diag

    // QK^T (swapped): lane holds S[q = qb*64+w*16+q15][k = kt*64+sub*32+8g+4nf+r]
    f32x4 st0[2], st1[2];
    {
      bf16x8 kf00, kf01, kf10, kf11;
      kf00 = *(const bf16x8*)(Ks + (0 * 32 + 0 * 16 + q15) * 128 + (((0 + g) ^ (q15 & 7)) << 4));
      kf01 = *(const bf16x8*)(Ks + (0 * 32 + 1 * 16 + q15) * 128 + (((0 + g) ^ (q15 & 7)) << 4));
      bf16x8 kh00 = *(const bf16x8*)(Ks + (0 * 32 + 0 * 16 + q15) * 128 + (((4 + g) ^ (q15 & 7)) << 4));
      bf16x8 kh01 = *(const bf16x8*)(Ks + (0 * 32 + 1 * 16 + q15) * 128 + (((4 + g) ^ (q15 & 7)) << 4));
      __builtin_amdgcn_s_setprio(1);
      st0[0] = mfma16(kf00, qf[0], FZ);
      st0[1] = mfma16(kf01, qf[0], FZ);
      st0[0] = mfma16(kh00, qf[1], st0[0]);
      st0[1] = mfma16(kh01, qf[1], st0[1]);
      __builtin_amdgcn_s_setprio(0);
      if (a1) {
        kf10 = *(const bf16x8*)(Ks + (32 + 0 * 16 + q15) * 128 + (((0 + g) ^ (q15 & 7)) << 4));
        kf11 = *(const bf16x8*)(Ks + (32 + 1 * 16 + q15) * 128 + (((0 + g) ^ (q15 & 7)) << 4));
        bf16x8 kh10 = *(const bf16x8*)(Ks + (32 + 0 * 16 + q15) * 128 + (((4 + g) ^ (q15 & 7)) << 4));
        bf16x8 kh11 = *(const bf16x8*)(Ks + (32 + 1 * 16 + q15) * 128 + (((4 + g) ^ (q15 & 7)) << 4));
        __builtin_amdgcn_s_setprio(1);
        st1[0] = mfma16(kf10, qf[0], FZ);
        st1[1] = mfma16(kf11, qf[0], FZ);
        st1[0] = mfma16(kh10, qf[1], st1[0]);
        st1[1] = mfma16(kh11, qf[1], st1[1]);
        __builtin_amdgcn_s_setprio(0);
      }
    }

    // causal mask: diagonal touches sub0 for waves 0,1; sub1 for waves 2,3
    if (diag) {
      int qg = qb * 64 + w * 16 + q15;
      if (w < 2) {
#pragma unroll
        for (int nf = 0; nf < 2; ++nf)
#pragma unroll
          for (int r = 0; r < 4; ++r) {
            int kg = kt * 64 + 8 * g + 4 * nf + r;
            if (kg > qg) st0[nf][r] = -1e30f;
          }
      } else {
#pragma unroll
        for (int nf = 0; nf < 2; ++nf)
#pragma unroll
          for (int r = 0; r < 4; ++r) {
            int kg = kt * 64 + 32 + 8 * g + 4 * nf + r;
            if (kg > qg) st1[nf][r] = -1e30f;
          }
      }
    }

    // combined softmax over the (up to) 64 kv of this iteration
    float vm = st0[0][0];
#pragma unroll
    for (int nf = 0; nf < 2; ++nf)
#pragma unroll
      for (int r = 0; r < 4; ++r) vm = fmaxf(vm, st0[nf][r]);
    if (a1) {
#pragma unroll
      for (int nf = 0; nf < 2; ++nf)
#pragma unroll
        for (int r = 0; r < 4; ++r) vm = fmaxf(vm, st1[nf][r]);
    }
    vm = fmaxf(vm, __shfl_xor(vm, 16, 64));
    vm = fmaxf(vm, __shfl_xor(vm, 32, 64));
    const bool resc = !__all(vm - m_r <= 8.0f);
    if (resc) {
      float mn = fmaxf(m_r, vm);
      float cr = EXP2(m_r - mn);
      m_r = mn;
      l_r *= cr;
      float cra[4];
#pragma unroll
      for (int r = 0; r < 4; ++r) cra[r] = __shfl(cr, 4 * g + r, 64);
#pragma unroll
      for (int nfd = 0; nfd < 4; ++nfd)
#pragma unroll
        for (int r = 0; r < 4; ++r) acc[nfd][r] *= cra[r];
    }

    float vs;
    bf16x8 pa0, pa1;
    {
      float p0 = EXP2(st0[0][0] - m_r), p1 = EXP2(st0[0][1] - m_r);
      float p2 = EXP2(st0[0][2] - m_r), p3 = EXP2(st0[0][3] - m_r);
      float p4 = EXP2(st0[1][0] - m_r), p5 = EXP2(st0[1][1] - m_r);
      float p6 = EXP2(st0[1][2] - m_r), p7 = EXP2(st0[1][3] - m_r);
      vs = ((p0 + p1) + (p2 + p3)) + ((p4 + p5) + (p6 + p7));
      u32x4 W;
      W.x = pk2bf(p0, p1); W.y = pk2bf(p2, p3);
      W.z = pk2bf(p4, p5); W.w = pk2bf(p6, p7);
      pa0 = __builtin_bit_cast(bf16x8, W);
    }
    if (a1) {
      float p0 = EXP2(st1[0][0] - m_r), p1 = EXP2(st1[0][1] - m_r);
      float p2 = EXP2(st1[0][2] - m_r), p3 = EXP2(st1[0][3] - m_r);
      float p4 = EXP2(st1[1][0] - m_r), p5 = EXP2(st1[1][1] - m_r);
      float p6 = EXP2(st1[1][2] - m_r), p7 = EXP2(st1[1][3] - m_r);
      vs += ((p0 + p1) + (p2 + p3)) + ((p4 + p5) + (p6 + p7));
      u32x4 W;
      W.x = pk2bf(p0, p1); W.y = pk2bf(p2, p3);
      W.z = pk2bf(p4, p5); W.w = pk2bf(p6, p7);
      pa1 = __builtin_bit_cast(bf16x8, W);
    }
    vs += __shfl_xor(vs, 16, 64);
    vs += __shfl_xor(vs, 32, 64);
    l_r += vs;

    // PV via K=32 MFMA: B-frag = V^T[d][k = kt*64 + sub*32 + 8g..8g+7]
#pragma unroll
    for (int nfd = 0; nfd < 4; ++nfd) {
      int d = nfd * 16 + q15;
      bf16x8 vb0 = *(const bf16x8*)(Vs + d * 128 + (((g ^ d) & 7) << 4));
      __builtin_amdgcn_s_setprio(1);
      acc[nfd] = mfma16(pa0, vb0, acc[nfd]);
      __builtin_amdgcn_s_setprio(0);
      if (a1) {
        bf16x8 vb1 = *(const bf16x8*)(Vs + d * 128 + ((((4 + g) ^ d) & 7) << 4));
        __builtin_amdgcn_s_setprio(1);
        acc[nfd] = mfma16(pa1, vb1, acc[nfd]);
        __builtin_amdgcn_s_setprio(0);
      }
    }
    cur ^= 1;
  }

  // epilogue: normalize (l lives at q = lane&15; acc rows at q' = 4g+r)
  u16* Og = O + ((size_t)(b * 2048 + qb * 64 + w * 16) * 2048 + h * 64);
  float la4[4];
#pragma unroll
  for (int r = 0; r < 4; ++r) la4[r] = __shfl(l_r, 4 * g + r, 64);
#pragma unroll
  for (int r = 0; r < 4; ++r) {
    float li = 1.f / la4[r];
#pragma unroll
    for (int nfd = 0; nfd < 4; ++nfd)
      Og[(size_t)(4 * g + r) * 2048 + nfd * 16 + q15] = f2bf(acc[nfd][r] * li);
  }
}

// ---------------------------------------------------------------------------
extern "C" void kernel_launch(void* const* d_in, const int* in_sizes, int n_in,
                              void* d_out, int out_size, void* d_ws, size_t ws_size,
                              hipStream_t stream) {
  const float* x = (const float*)d_in[0];
  const float* fc = (const float*)d_in[1];
  const float* fs = (const float*)d_in[2];
  const float* wq = (const float*)d_in[3];
  const float* wk = (const float*)d_in[4];
  const float* wv = (const float*)d_in[5];
  const float* wo = (const float*)d_in[6];
  float* out = (float*)d_out;
  char* ws = (char*)d_ws;

  // Workspace layout (64 MB):
  u16* xb    = (u16*)(ws);                 // [4096][2048] 16 MB (reused as attn O)
  u16* Qb    = (u16*)(ws + 16777216);      // [2][32][2048][64] 16 MB (roped, exp2-scaled)
  u16* Kb    = (u16*)(ws + 33554432);      // [2][8][2048][64]   4 MB (roped)
  u16* Vsl   = (u16*)(ws + 37748736);      // [4096][512]        4 MB
  u16* Vtb   = (u16*)(ws + 41943040);      // [2][8][64][2048]   4 MB
  u16* woT   = (u16*)(ws + 46137344);      // [2048][2048]       8 MB
  u16* wqkvT = (u16*)(ws + 54525952);      // [3072][2048]      12 MB
  u16* Obuf = xb;

  dim3 tb(32, 8);
  cvt_x<<<dim3(8192), dim3(256), 0, stream>>>(x, xb);
  tconv<<<dim3(64, 64), tb, 0, stream>>>(wq, wqkvT, 2048, 0, 2048);
  tconv<<<dim3(16, 64), tb, 0, stream>>>(wk, wqkvT, 512, 2048, 2048);
  tconv<<<dim3(16, 64), tb, 0, stream>>>(wv, wqkvT, 512, 2560, 2048);
  tconv<<<dim3(64, 64), tb, 0, stream>>>(wo, woT, 2048, 0, 2048);
  gemm_qkv<<<dim3(24, 32), dim3(256), 0, stream>>>(xb, wqkvT, fc, fs, Qb, Kb, Vsl);
  vtrans<<<dim3(64, 2, 16), tb, 0, stream>>>(Vsl, Vtb);
  attn<<<dim3(32, 32, 2), dim3(256), 0, stream>>>(Qb, Kb, Vtb, Obuf);
  gemm_bt<<<dim3(16, 32), dim3(256), 0, stream>>>(Obuf, woT, out, 4096, 2048, 2048);
}

// Round 10
// 203.838 us; speedup vs baseline: 1.1582x; 1.1582x over previous
//
#include <hip/hip_runtime.h>

typedef unsigned short u16;
typedef unsigned int u32;
typedef __bf16 bf16x4 __attribute__((ext_vector_type(4)));
typedef __bf16 bf16x8 __attribute__((ext_vector_type(8)));
typedef float f32x4 __attribute__((ext_vector_type(4)));
typedef u32 u32x4 __attribute__((ext_vector_type(4)));

struct __align__(4) U16x2 { u16 x, y; };
struct __align__(8) U16x4 { u16 x, y, z, w; };

#define DEV static __device__ __forceinline__

extern "C" __device__ float __ocml_exp2_f32(float);
#if __has_builtin(__builtin_amdgcn_exp2f)
#define EXP2(x) __builtin_amdgcn_exp2f(x)
#else
#define EXP2(x) __ocml_exp2_f32(x)
#endif

DEV u16 f2bf(float f) {
  __bf16 h = (__bf16)f;
  return __builtin_bit_cast(u16, h);
}
DEV u32 pk2bf(float lo, float hi) { return (u32)f2bf(lo) | ((u32)f2bf(hi) << 16); }

DEV void gload16(const void* g, void* l) {
  __builtin_amdgcn_global_load_lds((const __attribute__((address_space(1))) char*)g,
                                   (__attribute__((address_space(3))) char*)l, 16, 0, 0);
}

DEV f32x4 mfma16(bf16x8 a, bf16x8 b, f32x4 c) {
  return __builtin_amdgcn_mfma_f32_16x16x32_bf16(a, b, c, 0, 0, 0);
}

// ---------------------------------------------------------------------------
// x fp32 -> bf16, 4 elems/thread
__global__ __launch_bounds__(256) void cvt_x(const float* __restrict__ x, u16* __restrict__ xb) {
  int i = blockIdx.x * 256 + threadIdx.x;
  float4 v = ((const float4*)x)[i];
  U16x4 o;
  o.x = f2bf(v.x); o.y = f2bf(v.y); o.z = f2bf(v.z); o.w = f2bf(v.w);
  ((U16x4*)xb)[i] = o;
}

// ---------------------------------------------------------------------------
// fp32 [R][C] -> bf16 dst[nOff + c][r] (transposed), ldd = R
__global__ __launch_bounds__(256) void tconv(const float* __restrict__ src, u16* __restrict__ dst,
                                             int C, int nOff, int ldd) {
  __shared__ float t[32][33];
  int bx = blockIdx.x, by = blockIdx.y;
  int tx = threadIdx.x, ty = threadIdx.y;
#pragma unroll
  for (int j = 0; j < 4; ++j)
    t[ty + 8 * j][tx] = src[(size_t)(by * 32 + ty + 8 * j) * C + bx * 32 + tx];
  __syncthreads();
#pragma unroll
  for (int j = 0; j < 4; ++j)
    dst[(size_t)(nOff + bx * 32 + ty + 8 * j) * ldd + by * 32 + tx] = f2bf(t[tx][ty + 8 * j]);
}

// ---------------------------------------------------------------------------
// bf16 V-slice [4096][512] -> Vt[(b*8+kh)*64+d][s]  (plain transpose)
__global__ __launch_bounds__(256) void vtrans(const u16* __restrict__ Vsl, u16* __restrict__ Vt) {
  __shared__ u16 t[32][33];
  int bx = blockIdx.x, by = blockIdx.y, bz = blockIdx.z;
  int tx = threadIdx.x, ty = threadIdx.y;
  int b = bz >> 3, kh = bz & 7;
  const u16* src = Vsl + (size_t)(b * 2048 + bx * 32) * 512 + kh * 64 + by * 32;
#pragma unroll
  for (int j = 0; j < 4; ++j) t[ty + 8 * j][tx] = src[(size_t)(ty + 8 * j) * 512 + tx];
  __syncthreads();
  u16* dst = Vt + ((size_t)bz * 64 + by * 32) * 2048 + bx * 32;
#pragma unroll
  for (int j = 0; j < 4; ++j) dst[(size_t)(ty + 8 * j) * 2048 + tx] = t[tx][ty + 8 * j];
}

// ---------------------------------------------------------------------------
// QKV GEMM with fused RoPE epilogue. C = A[4096][2048] * BT[3072][2048]^T.
// Epilogue routes: col<2048 -> Q (roped, pre-scaled 0.125*log2e), col<2560 ->
// K (roped), else -> compact V-slice [4096][512]. RoPE pair (d even, d odd)
// lives in adjacent lanes of the C fragment -> one __shfl_xor(v,1).
__global__ __launch_bounds__(256, 2) void gemm_qkv(const u16* __restrict__ A,
                                                   const u16* __restrict__ BT,
                                                   const float* __restrict__ fc,
                                                   const float* __restrict__ fs,
                                                   u16* __restrict__ Qo,
                                                   u16* __restrict__ Ko,
                                                   u16* __restrict__ Vsl) {
  __shared__ __align__(16) char smem[65536];
  const int tid = threadIdx.x;
  const int lane = tid & 63;
  const int wm = (tid >> 7) & 1, wn = (tid >> 6) & 1;
  const int tm = blockIdx.y, tn = blockIdx.x;
  const int K = 2048, Kb = 4096;

  f32x4 acc[4][4];
#pragma unroll
  for (int i = 0; i < 4; ++i)
#pragma unroll
    for (int j = 0; j < 4; ++j) acc[i][j] = (f32x4){0.f, 0.f, 0.f, 0.f};

  const char* Ag = (const char*)A + (size_t)tm * 128 * Kb;
  const char* Bg = (const char*)BT + (size_t)tn * 128 * Kb;

  auto stage = [&](int buf, int t) {
#pragma unroll
    for (int i = 0; i < 4; ++i) {
      int vt = i * 256 + tid;
      int row = vt >> 3;
      int cb = (((vt & 7) << 4) ^ ((row & 7) << 4));
      gload16(Ag + (size_t)row * Kb + t * 128 + cb, smem + buf * 16384 + vt * 16);
      gload16(Bg + (size_t)row * Kb + t * 128 + cb, smem + 32768 + buf * 16384 + vt * 16);
    }
  };

  stage(0, 0);
  int cur = 0;
  const int NT = K >> 6;
  for (int t = 0; t < NT; ++t) {
    __syncthreads();
    if (t + 1 < NT) stage(cur ^ 1, t + 1);
    const char* As = smem + cur * 16384;
    const char* Bs = smem + 32768 + cur * 16384;
#pragma unroll
    for (int ks = 0; ks < 2; ++ks) {
      bf16x8 a[4], b[4];
#pragma unroll
      for (int mf = 0; mf < 4; ++mf) {
        int row = wm * 64 + mf * 16 + (lane & 15);
        int cb = (ks * 64 + ((lane >> 4) << 4)) ^ ((row & 7) << 4);
        a[mf] = *(const bf16x8*)(As + row * 128 + cb);
      }
#pragma unroll
      for (int nf = 0; nf < 4; ++nf) {
        int row = wn * 64 + nf * 16 + (lane & 15);
        int cb = (ks * 64 + ((lane >> 4) << 4)) ^ ((row & 7) << 4);
        b[nf] = *(const bf16x8*)(Bs + row * 128 + cb);
      }
#pragma unroll
      for (int mf = 0; mf < 4; ++mf)
#pragma unroll
        for (int nf = 0; nf < 4; ++nf) acc[mf][nf] = mfma16(a[mf], b[nf], acc[mf][nf]);
    }
    cur ^= 1;
  }

  const float QS = 0.18033688011112042f;  // 0.125 * log2(e)
#pragma unroll
  for (int mf = 0; mf < 4; ++mf) {
    int row0 = tm * 128 + wm * 64 + mf * 16 + ((lane >> 4) << 2);
#pragma unroll
    for (int nf = 0; nf < 4; ++nf) {
      int col = tn * 128 + wn * 64 + nf * 16 + (lane & 15);
      if (col < 2560) {  // Q or K: apply RoPE
        int d = col & 63, d2 = d >> 1;
        bool ev = !(col & 1);
        bool isQ = (col < 2048);
        int hh = isQ ? (col >> 6) : ((col - 2048) >> 6);
#pragma unroll
        for (int r = 0; r < 4; ++r) {
          int row = row0 + r;
          int bb = row >> 11, s = row & 2047;
          float v = acc[mf][nf][r];
          float p = __shfl_xor(v, 1, 64);
          float c = fc[s * 32 + d2], sn = fs[s * 32 + d2];
          if (isQ) { c *= QS; sn *= QS; }
          float o = ev ? (v * c - p * sn) : (v * c + p * sn);
          if (isQ)
            Qo[((size_t)(bb * 32 + hh) * 2048 + s) * 64 + d] = f2bf(o);
          else
            Ko[((size_t)(bb * 8 + hh) * 2048 + s) * 64 + d] = f2bf(o);
        }
      } else {  // V slice, plain
#pragma unroll
        for (int r = 0; r < 4; ++r)
          Vsl[(size_t)(row0 + r) * 512 + (col - 2560)] = f2bf(acc[mf][nf][r]);
      }
    }
  }
}

// ---------------------------------------------------------------------------
// C[M][N] = A[M][K] * BT[N][K]^T  (bf16 in, float out) -- WO GEMM.
__global__ __launch_bounds__(256, 2) void gemm_bt(const u16* __restrict__ A,
                                                  const u16* __restrict__ BT,
                                                  float* __restrict__ C,
                                                  int M, int N, int K) {
  __shared__ __align__(16) char smem[65536];
  const int tid = threadIdx.x;
  const int lane = tid & 63;
  const int wm = (tid >> 7) & 1, wn = (tid >> 6) & 1;
  const int tm = blockIdx.y, tn = blockIdx.x;
  const int Kb = K * 2;

  f32x4 acc[4][4];
#pragma unroll
  for (int i = 0; i < 4; ++i)
#pragma unroll
    for (int j = 0; j < 4; ++j) acc[i][j] = (f32x4){0.f, 0.f, 0.f, 0.f};

  const char* Ag = (const char*)A + (size_t)tm * 128 * Kb;
  const char* Bg = (const char*)BT + (size_t)tn * 128 * Kb;

  auto stage = [&](int buf, int t) {
#pragma unroll
    for (int i = 0; i < 4; ++i) {
      int vt = i * 256 + tid;
      int row = vt >> 3;
      int cb = (((vt & 7) << 4) ^ ((row & 7) << 4));
      gload16(Ag + (size_t)row * Kb + t * 128 + cb, smem + buf * 16384 + vt * 16);
      gload16(Bg + (size_t)row * Kb + t * 128 + cb, smem + 32768 + buf * 16384 + vt * 16);
    }
  };

  stage(0, 0);
  int cur = 0;
  const int NT = K >> 6;
  for (int t = 0; t < NT; ++t) {
    __syncthreads();
    if (t + 1 < NT) stage(cur ^ 1, t + 1);
    const char* As = smem + cur * 16384;
    const char* Bs = smem + 32768 + cur * 16384;
#pragma unroll
    for (int ks = 0; ks < 2; ++ks) {
      bf16x8 a[4], b[4];
#pragma unroll
      for (int mf = 0; mf < 4; ++mf) {
        int row = wm * 64 + mf * 16 + (lane & 15);
        int cb = (ks * 64 + ((lane >> 4) << 4)) ^ ((row & 7) << 4);
        a[mf] = *(const bf16x8*)(As + row * 128 + cb);
      }
#pragma unroll
      for (int nf = 0; nf < 4; ++nf) {
        int row = wn * 64 + nf * 16 + (lane & 15);
        int cb = (ks * 64 + ((lane >> 4) << 4)) ^ ((row & 7) << 4);
        b[nf] = *(const bf16x8*)(Bs + row * 128 + cb);
      }
#pragma unroll
      for (int mf = 0; mf < 4; ++mf)
#pragma unroll
        for (int nf = 0; nf < 4; ++nf) acc[mf][nf] = mfma16(a[mf], b[nf], acc[mf][nf]);
    }
    cur ^= 1;
  }
#pragma unroll
  for (int mf = 0; mf < 4; ++mf) {
    int row0 = tm * 128 + wm * 64 + mf * 16 + ((lane >> 4) << 2);
#pragma unroll
    for (int nf = 0; nf < 4; ++nf) {
      int col = tn * 128 + wn * 64 + nf * 16 + (lane & 15);
#pragma unroll
      for (int r = 0; r < 4; ++r)
        C[(size_t)(row0 + r) * N + col] = acc[mf][nf][r];
    }
  }
}

// ---------------------------------------------------------------------------
// Causal GQA flash attention (R8 structure): dual-tile waves, swapped QK^T,
// in-register P, PV via K=32 MFMA through a kv-permuted K tile, KVBLK=32,
// fully resident (2048 blocks x 128 thr x 16KB LDS = 8 blocks/CU, balanced).
// R10 delta: NO cross-lane ops in the common softmax path -- per-lane max
// feeds the T13 defer check directly, and l is accumulated as a per-lane
// partial, reduced across lane-groups once in the epilogue.
__global__ __launch_bounds__(128, 4) void attn(const u16* __restrict__ Q,
                                               const u16* __restrict__ Kt,
                                               const u16* __restrict__ Vt,
                                               u16* __restrict__ O) {
  __shared__ __align__(16) char smem[16384];  // per buf: K 4KB + V 4KB

  const int tid = threadIdx.x, lane = tid & 63, w = tid >> 6;  // w in {0,1}
  const int q15 = lane & 15, g = lane >> 4;
  const int bx = blockIdx.x, h = blockIdx.y, b = blockIdx.z;
  const int kh = h >> 2;
  const int QT0 = 63 - bx, QT1 = bx;  // heavy, light q-tiles (32 rows each)

  const char* Qg = (const char*)(Q + ((size_t)(b * 32 + h) * 2048) * 64);
  const char* Kg = (const char*)(Kt + ((size_t)(b * 8 + kh) * 2048 * 64));
  const char* Vg = (const char*)(Vt + ((size_t)(b * 8 + kh) * 64 * 2048));

  // Q fragments (B-operand of swapped QK^T), both tiles
  bf16x8 qf0[2], qf1[2];
#pragma unroll
  for (int ks = 0; ks < 2; ++ks) {
    int r0 = QT0 * 32 + w * 16 + q15;
    int r1 = QT1 * 32 + w * 16 + q15;
    qf0[ks] = *(const bf16x8*)(Qg + (size_t)r0 * 128 + ks * 64 + (g << 4));
    qf1[ks] = *(const bf16x8*)(Qg + (size_t)r1 * 128 + ks * 64 + (g << 4));
  }

  f32x4 acc0[4], acc1[4];
#pragma unroll
  for (int j = 0; j < 4; ++j) {
    acc0[j] = (f32x4){0.f, 0.f, 0.f, 0.f};
    acc1[j] = (f32x4){0.f, 0.f, 0.f, 0.f};
  }
  float m0 = -1e30f, m1 = -1e30f, l0 = 0.f, l1 = 0.f;
  const f32x4 FZ = (f32x4){0.f, 0.f, 0.f, 0.f};

  auto stageKV = [&](int buf, int kt) {
#pragma unroll
    for (int i = 0; i < 2; ++i) {
      int vt = i * 128 + tid;  // 0..255
      // K: LDS row rho holds global kv row kappa(rho) = 8g'+4nf'+r'
      int rho = vt >> 3, ck = vt & 7;
      int kap = ((rho & 12) << 1) + ((rho & 16) >> 2) + (rho & 3);
      gload16(Kg + (size_t)(kt * 32 + kap) * 128 + (((ck ^ rho) & 7) << 4),
              smem + buf * 8192 + vt * 16);
      // V: natural kv order, 64 d-rows x 64B, chunk swizzle ^((d>>1)&3)
      int d = vt >> 2, cv = vt & 3;
      gload16(Vg + (size_t)d * 4096 + kt * 64 + (((cv ^ (d >> 1)) & 3) << 4),
              smem + buf * 8192 + 4096 + vt * 16);
    }
  };

  stageKV(0, 0);
  int cur = 0;
  const int nkt = QT0 + 1;
  for (int kt = 0; kt < nkt; ++kt) {
    __syncthreads();  // KV[cur] staged (compiler drains vmcnt before barrier)
    if (kt + 1 < nkt) stageKV(cur ^ 1, kt + 1);
    const char* Ks = smem + cur * 8192;
    const char* Vs = smem + cur * 8192 + 4096;
    const bool la = (kt <= QT1);  // light tile active

    // K fragments (A-operand), shared by both tiles
    bf16x8 kf[2][2];  // [ks][nf]
#pragma unroll
    for (int ks = 0; ks < 2; ++ks)
#pragma unroll
      for (int nf = 0; nf < 2; ++nf) {
        int r = nf * 16 + q15;
        int c = (4 * ks + g) ^ (r & 7);
        kf[ks][nf] = *(const bf16x8*)(Ks + r * 128 + (c << 4));
      }

    // swapped QK^T: lane holds S[q = Qt*32+w*16+q15][k = kt*32 + 8g+4nf+r]
    f32x4 st0[2], st1[2];
    __builtin_amdgcn_s_setprio(1);
#pragma unroll
    for (int nf = 0; nf < 2; ++nf) {
      st0[nf] = mfma16(kf[0][nf], qf0[0], FZ);
      st0[nf] = mfma16(kf[1][nf], qf0[1], st0[nf]);
    }
    if (la) {
#pragma unroll
      for (int nf = 0; nf < 2; ++nf) {
        st1[nf] = mfma16(kf[0][nf], qf1[0], FZ);
        st1[nf] = mfma16(kf[1][nf], qf1[1], st1[nf]);
      }
    }
    __builtin_amdgcn_s_setprio(0);

    // causal mask on each tile's diagonal step (k = kt*32 + 8g + 4nf + r)
    if (kt == QT0) {
      int qg = QT0 * 32 + w * 16 + q15;
#pragma unroll
      for (int nf = 0; nf < 2; ++nf)
#pragma unroll
        for (int r = 0; r < 4; ++r) {
          int kg = kt * 32 + 8 * g + 4 * nf + r;
          if (kg > qg) st0[nf][r] = -1e30f;
        }
    }
    if (la && kt == QT1) {
      int qg = QT1 * 32 + w * 16 + q15;
#pragma unroll
      for (int nf = 0; nf < 2; ++nf)
#pragma unroll
        for (int r = 0; r < 4; ++r) {
          int kg = kt * 32 + 8 * g + 4 * nf + r;
          if (kg > qg) st1[nf][r] = -1e30f;
        }
    }

    // softmax (exp2 domain): common path has ZERO cross-lane ops.
    bf16x8 pa0, pa1;
#pragma unroll
    for (int t = 0; t < 2; ++t) {
      if (t == 1 && !la) break;
      f32x4* st = (t == 0) ? st0 : st1;
      float& m_r = (t == 0) ? m0 : m1;
      float& l_r = (t == 0) ? l0 : l1;
      f32x4* accT = (t == 0) ? acc0 : acc1;

      // per-lane max over this lane's 8 S values (tree, 7 fmax)
      float vm = fmaxf(fmaxf(fmaxf(st[0][0], st[0][1]), fmaxf(st[0][2], st[0][3])),
                       fmaxf(fmaxf(st[1][0], st[1][1]), fmaxf(st[1][2], st[1][3])));
      // T13 defer-rescale: __all on per-lane max == check on the global max.
      if (!__all(vm - m_r <= 8.0f)) {
        vm = fmaxf(vm, __shfl_xor(vm, 16, 64));
        vm = fmaxf(vm, __shfl_xor(vm, 32, 64));
        float mn = fmaxf(m_r, vm);
        float cr = EXP2(m_r - mn);
        m_r = mn;
        l_r *= cr;  // per-lane partial; cr is row-uniform across g
        float cra[4];
#pragma unroll
        for (int r = 0; r < 4; ++r) cra[r] = __shfl(cr, 4 * g + r, 64);
#pragma unroll
        for (int nfd = 0; nfd < 4; ++nfd)
#pragma unroll
          for (int r = 0; r < 4; ++r) accT[nfd][r] *= cra[r];
      }
      // P = exp2(S - m); pack into the K=32 A-fragment; per-lane l partial
      float p0 = EXP2(st[0][0] - m_r), p1 = EXP2(st[0][1] - m_r);
      float p2 = EXP2(st[0][2] - m_r), p3 = EXP2(st[0][3] - m_r);
      float p4 = EXP2(st[1][0] - m_r), p5 = EXP2(st[1][1] - m_r);
      float p6 = EXP2(st[1][2] - m_r), p7 = EXP2(st[1][3] - m_r);
      l_r += ((p0 + p1) + (p2 + p3)) + ((p4 + p5) + (p6 + p7));
      u32x4 W;
      W.x = pk2bf(p0, p1);
      W.y = pk2bf(p2, p3);
      W.z = pk2bf(p4, p5);
      W.w = pk2bf(p6, p7);
      if (t == 0) pa0 = __builtin_bit_cast(bf16x8, W);
      else pa1 = __builtin_bit_cast(bf16x8, W);
    }

    // PV via K=32 MFMA: B-frag = V^T[d = nfd*16+q15][k = kt*32 + 8g..8g+7]
#pragma unroll
    for (int nfd = 0; nfd < 4; ++nfd) {
      int d = nfd * 16 + q15;
      int c = (g ^ (d >> 1)) & 3;
      bf16x8 vb = *(const bf16x8*)(Vs + d * 64 + (c << 4));
      __builtin_amdgcn_s_setprio(1);
      acc0[nfd] = mfma16(pa0, vb, acc0[nfd]);
      if (la) acc1[nfd] = mfma16(pa1, vb, acc1[nfd]);
      __builtin_amdgcn_s_setprio(0);
    }
    cur ^= 1;
  }

  // epilogue: reduce per-lane l partials across g (deferred from the loop),
  // then normalize (l lives at q = lane&15; acc rows at q' = 4g+r).
#pragma unroll
  for (int t = 0; t < 2; ++t) {
    float l_r = (t == 0) ? l0 : l1;
    l_r += __shfl_xor(l_r, 16, 64);
    l_r += __shfl_xor(l_r, 32, 64);
    f32x4* accT = (t == 0) ? acc0 : acc1;
    int qt = (t == 0) ? QT0 : QT1;
    u16* Og = O + ((size_t)(b * 2048 + qt * 32 + w * 16) * 2048 + h * 64);
    float la4[4];
#pragma unroll
    for (int r = 0; r < 4; ++r) la4[r] = __shfl(l_r, 4 * g + r, 64);
#pragma unroll
    for (int r = 0; r < 4; ++r) {
      float li = 1.f / la4[r];
#pragma unroll
      for (int nfd = 0; nfd < 4; ++nfd)
        Og[(size_t)(4 * g + r) * 2048 + nfd * 16 + q15] = f2bf(accT[nfd][r] * li);
    }
  }
}

// ---------------------------------------------------------------------------
extern "C" void kernel_launch(void* const* d_in, const int* in_sizes, int n_in,
                              void* d_out, int out_size, void* d_ws, size_t ws_size,
                              hipStream_t stream) {
  const float* x = (const float*)d_in[0];
  const float* fc = (const float*)d_in[1];
  const float* fs = (const float*)d_in[2];
  const float* wq = (const float*)d_in[3];
  const float* wk = (const float*)d_in[4];
  const float* wv = (const float*)d_in[5];
  const float* wo = (const float*)d_in[6];
  float* out = (float*)d_out;
  char* ws = (char*)d_ws;

  // Workspace layout (64 MB):
  u16* xb    = (u16*)(ws);                 // [4096][2048] 16 MB (reused as attn O)
  u16* Qb    = (u16*)(ws + 16777216);      // [2][32][2048][64] 16 MB (roped, exp2-scaled)
  u16* Kb    = (u16*)(ws + 33554432);      // [2][8][2048][64]   4 MB (roped)
  u16* Vsl   = (u16*)(ws + 37748736);      // [4096][512]        4 MB
  u16* Vtb   = (u16*)(ws + 41943040);      // [2][8][64][2048]   4 MB
  u16* woT   = (u16*)(ws + 46137344);      // [2048][2048]       8 MB
  u16* wqkvT = (u16*)(ws + 54525952);      // [3072][2048]      12 MB
  u16* Obuf = xb;

  dim3 tb(32, 8);
  cvt_x<<<dim3(8192), dim3(256), 0, stream>>>(x, xb);
  tconv<<<dim3(64, 64), tb, 0, stream>>>(wq, wqkvT, 2048, 0, 2048);
  tconv<<<dim3(16, 64), tb, 0, stream>>>(wk, wqkvT, 512, 2048, 2048);
  tconv<<<dim3(16, 64), tb, 0, stream>>>(wv, wqkvT, 512, 2560, 2048);
  tconv<<<dim3(64, 64), tb, 0, stream>>>(wo, woT, 2048, 0, 2048);
  gemm_qkv<<<dim3(24, 32), dim3(256), 0, stream>>>(xb, wqkvT, fc, fs, Qb, Kb, Vsl);
  vtrans<<<dim3(64, 2, 16), tb, 0, stream>>>(Vsl, Vtb);
  attn<<<dim3(32, 32, 2), dim3(128), 0, stream>>>(Qb, Kb, Vtb, Obuf);
  gemm_bt<<<dim3(16, 32), dim3(256), 0, stream>>>(Obuf, woT, out, 4096, 2048, 2048);
}

// Round 11
// 194.503 us; speedup vs baseline: 1.2138x; 1.0480x over previous
//
#include <hip/hip_runtime.h>

typedef unsigned short u16;
typedef unsigned int u32;
typedef __bf16 bf16x4 __attribute__((ext_vector_type(4)));
typedef __bf16 bf16x8 __attribute__((ext_vector_type(8)));
typedef float f32x4 __attribute__((ext_vector_type(4)));
typedef u32 u32x4 __attribute__((ext_vector_type(4)));

struct __align__(4) U16x2 { u16 x, y; };
struct __align__(8) U16x4 { u16 x, y, z, w; };

#define DEV static __device__ __forceinline__

extern "C" __device__ float __ocml_exp2_f32(float);
#if __has_builtin(__builtin_amdgcn_exp2f)
#define EXP2(x) __builtin_amdgcn_exp2f(x)
#else
#define EXP2(x) __ocml_exp2_f32(x)
#endif

DEV u16 f2bf(float f) {
  __bf16 h = (__bf16)f;
  return __builtin_bit_cast(u16, h);
}
DEV u32 pk2bf(float lo, float hi) { return (u32)f2bf(lo) | ((u32)f2bf(hi) << 16); }

DEV void gload16(const void* g, void* l) {
  __builtin_amdgcn_global_load_lds((const __attribute__((address_space(1))) char*)g,
                                   (__attribute__((address_space(3))) char*)l, 16, 0, 0);
}

DEV f32x4 mfma16(bf16x8 a, bf16x8 b, f32x4 c) {
  return __builtin_amdgcn_mfma_f32_16x16x32_bf16(a, b, c, 0, 0, 0);
}

// ---------------------------------------------------------------------------
// Merged prep: one launch does x fp32->bf16 (blocks [0,8192)) and the four
// weight transpose+converts (blocks [8192,18432)). Branch is block-uniform.
__global__ __launch_bounds__(256) void prep(const float* __restrict__ x,
                                            const float* __restrict__ wq,
                                            const float* __restrict__ wk,
                                            const float* __restrict__ wv,
                                            const float* __restrict__ wo,
                                            u16* __restrict__ xb,
                                            u16* __restrict__ wqkvT,
                                            u16* __restrict__ woT) {
  __shared__ float t[32][33];
  int id = blockIdx.x;
  int tx = threadIdx.x, ty = threadIdx.y;
  if (id < 8192) {  // cvt_x: 4 fp32 -> 4 bf16 per thread
    int i = id * 256 + ty * 32 + tx;
    float4 v = ((const float4*)x)[i];
    U16x4 o;
    o.x = f2bf(v.x); o.y = f2bf(v.y); o.z = f2bf(v.z); o.w = f2bf(v.w);
    ((U16x4*)xb)[i] = o;
    return;
  }
  id -= 8192;
  const float* src;
  u16* dst;
  int C, nOff, gx;
  if (id < 4096)      { src = wq; dst = wqkvT; C = 2048; nOff = 0;    gx = 64; }
  else if (id < 5120) { id -= 4096; src = wk; dst = wqkvT; C = 512; nOff = 2048; gx = 16; }
  else if (id < 6144) { id -= 5120; src = wv; dst = wqkvT; C = 512; nOff = 2560; gx = 16; }
  else                { id -= 6144; src = wo; dst = woT;   C = 2048; nOff = 0;   gx = 64; }
  int bx = id % gx, by = id / gx;
#pragma unroll
  for (int j = 0; j < 4; ++j)
    t[ty + 8 * j][tx] = src[(size_t)(by * 32 + ty + 8 * j) * C + bx * 32 + tx];
  __syncthreads();
#pragma unroll
  for (int j = 0; j < 4; ++j)
    dst[(size_t)(nOff + bx * 32 + ty + 8 * j) * 2048 + by * 32 + tx] = f2bf(t[tx][ty + 8 * j]);
}

// ---------------------------------------------------------------------------
// bf16 V-slice [4096][512] -> Vt[(b*8+kh)*64+d][s]  (plain transpose)
__global__ __launch_bounds__(256) void vtrans(const u16* __restrict__ Vsl, u16* __restrict__ Vt) {
  __shared__ u16 t[32][33];
  int bx = blockIdx.x, by = blockIdx.y, bz = blockIdx.z;
  int tx = threadIdx.x, ty = threadIdx.y;
  int b = bz >> 3, kh = bz & 7;
  const u16* src = Vsl + (size_t)(b * 2048 + bx * 32) * 512 + kh * 64 + by * 32;
#pragma unroll
  for (int j = 0; j < 4; ++j) t[ty + 8 * j][tx] = src[(size_t)(ty + 8 * j) * 512 + tx];
  __syncthreads();
  u16* dst = Vt + ((size_t)bz * 64 + by * 32) * 2048 + bx * 32;
#pragma unroll
  for (int j = 0; j < 4; ++j) dst[(size_t)(ty + 8 * j) * 2048 + tx] = t[tx][ty + 8 * j];
}

// ---------------------------------------------------------------------------
// QKV GEMM with fused RoPE epilogue. C = A[4096][2048] * BT[3072][2048]^T.
// Epilogue routes: col<2048 -> Q (roped, pre-scaled 0.125*log2e), col<2560 ->
// K (roped), else -> compact V-slice [4096][512]. RoPE pair (d even, d odd)
// lives in adjacent lanes of the C fragment -> one __shfl_xor(v,1).
__global__ __launch_bounds__(256, 2) void gemm_qkv(const u16* __restrict__ A,
                                                   const u16* __restrict__ BT,
                                                   const float* __restrict__ fc,
                                                   const float* __restrict__ fs,
                                                   u16* __restrict__ Qo,
                                                   u16* __restrict__ Ko,
                                                   u16* __restrict__ Vsl) {
  __shared__ __align__(16) char smem[65536];
  const int tid = threadIdx.x;
  const int lane = tid & 63;
  const int wm = (tid >> 7) & 1, wn = (tid >> 6) & 1;
  const int tm = blockIdx.y, tn = blockIdx.x;
  const int K = 2048, Kb = 4096;

  f32x4 acc[4][4];
#pragma unroll
  for (int i = 0; i < 4; ++i)
#pragma unroll
    for (int j = 0; j < 4; ++j) acc[i][j] = (f32x4){0.f, 0.f, 0.f, 0.f};

  const char* Ag = (const char*)A + (size_t)tm * 128 * Kb;
  const char* Bg = (const char*)BT + (size_t)tn * 128 * Kb;

  auto stage = [&](int buf, int t) {
#pragma unroll
    for (int i = 0; i < 4; ++i) {
      int vt = i * 256 + tid;
      int row = vt >> 3;
      int cb = (((vt & 7) << 4) ^ ((row & 7) << 4));
      gload16(Ag + (size_t)row * Kb + t * 128 + cb, smem + buf * 16384 + vt * 16);
      gload16(Bg + (size_t)row * Kb + t * 128 + cb, smem + 32768 + buf * 16384 + vt * 16);
    }
  };

  stage(0, 0);
  int cur = 0;
  const int NT = K >> 6;
  for (int t = 0; t < NT; ++t) {
    __syncthreads();
    if (t + 1 < NT) stage(cur ^ 1, t + 1);
    const char* As = smem + cur * 16384;
    const char* Bs = smem + 32768 + cur * 16384;
#pragma unroll
    for (int ks = 0; ks < 2; ++ks) {
      bf16x8 a[4], b[4];
#pragma unroll
      for (int mf = 0; mf < 4; ++mf) {
        int row = wm * 64 + mf * 16 + (lane & 15);
        int cb = (ks * 64 + ((lane >> 4) << 4)) ^ ((row & 7) << 4);
        a[mf] = *(const bf16x8*)(As + row * 128 + cb);
      }
#pragma unroll
      for (int nf = 0; nf < 4; ++nf) {
        int row = wn * 64 + nf * 16 + (lane & 15);
        int cb = (ks * 64 + ((lane >> 4) << 4)) ^ ((row & 7) << 4);
        b[nf] = *(const bf16x8*)(Bs + row * 128 + cb);
      }
#pragma unroll
      for (int mf = 0; mf < 4; ++mf)
#pragma unroll
        for (int nf = 0; nf < 4; ++nf) acc[mf][nf] = mfma16(a[mf], b[nf], acc[mf][nf]);
    }
    cur ^= 1;
  }

  const float QS = 0.18033688011112042f;  // 0.125 * log2(e)
#pragma unroll
  for (int mf = 0; mf < 4; ++mf) {
    int row0 = tm * 128 + wm * 64 + mf * 16 + ((lane >> 4) << 2);
#pragma unroll
    for (int nf = 0; nf < 4; ++nf) {
      int col = tn * 128 + wn * 64 + nf * 16 + (lane & 15);
      if (col < 2560) {  // Q or K: apply RoPE
        int d = col & 63, d2 = d >> 1;
        bool ev = !(col & 1);
        bool isQ = (col < 2048);
        int hh = isQ ? (col >> 6) : ((col - 2048) >> 6);
#pragma unroll
        for (int r = 0; r < 4; ++r) {
          int row = row0 + r;
          int bb = row >> 11, s = row & 2047;
          float v = acc[mf][nf][r];
          float p = __shfl_xor(v, 1, 64);
          float c = fc[s * 32 + d2], sn = fs[s * 32 + d2];
          if (isQ) { c *= QS; sn *= QS; }
          float o = ev ? (v * c - p * sn) : (v * c + p * sn);
          if (isQ)
            Qo[((size_t)(bb * 32 + hh) * 2048 + s) * 64 + d] = f2bf(o);
          else
            Ko[((size_t)(bb * 8 + hh) * 2048 + s) * 64 + d] = f2bf(o);
        }
      } else {  // V slice, plain
#pragma unroll
        for (int r = 0; r < 4; ++r)
          Vsl[(size_t)(row0 + r) * 512 + (col - 2560)] = f2bf(acc[mf][nf][r]);
      }
    }
  }
}

// ---------------------------------------------------------------------------
// C[M][N] = A[M][K] * BT[N][K]^T  (bf16 in, float out) -- WO GEMM.
__global__ __launch_bounds__(256, 2) void gemm_bt(const u16* __restrict__ A,
                                                  const u16* __restrict__ BT,
                                                  float* __restrict__ C,
                                                  int M, int N, int K) {
  __shared__ __align__(16) char smem[65536];
  const int tid = threadIdx.x;
  const int lane = tid & 63;
  const int wm = (tid >> 7) & 1, wn = (tid >> 6) & 1;
  const int tm = blockIdx.y, tn = blockIdx.x;
  const int Kb = K * 2;

  f32x4 acc[4][4];
#pragma unroll
  for (int i = 0; i < 4; ++i)
#pragma unroll
    for (int j = 0; j < 4; ++j) acc[i][j] = (f32x4){0.f, 0.f, 0.f, 0.f};

  const char* Ag = (const char*)A + (size_t)tm * 128 * Kb;
  const char* Bg = (const char*)BT + (size_t)tn * 128 * Kb;

  auto stage = [&](int buf, int t) {
#pragma unroll
    for (int i = 0; i < 4; ++i) {
      int vt = i * 256 + tid;
      int row = vt >> 3;
      int cb = (((vt & 7) << 4) ^ ((row & 7) << 4));
      gload16(Ag + (size_t)row * Kb + t * 128 + cb, smem + buf * 16384 + vt * 16);
      gload16(Bg + (size_t)row * Kb + t * 128 + cb, smem + 32768 + buf * 16384 + vt * 16);
    }
  };

  stage(0, 0);
  int cur = 0;
  const int NT = K >> 6;
  for (int t = 0; t < NT; ++t) {
    __syncthreads();
    if (t + 1 < NT) stage(cur ^ 1, t + 1);
    const char* As = smem + cur * 16384;
    const char* Bs = smem + 32768 + cur * 16384;
#pragma unroll
    for (int ks = 0; ks < 2; ++ks) {
      bf16x8 a[4], b[4];
#pragma unroll
      for (int mf = 0; mf < 4; ++mf) {
        int row = wm * 64 + mf * 16 + (lane & 15);
        int cb = (ks * 64 + ((lane >> 4) << 4)) ^ ((row & 7) << 4);
        a[mf] = *(const bf16x8*)(As + row * 128 + cb);
      }
#pragma unroll
      for (int nf = 0; nf < 4; ++nf) {
        int row = wn * 64 + nf * 16 + (lane & 15);
        int cb = (ks * 64 + ((lane >> 4) << 4)) ^ ((row & 7) << 4);
        b[nf] = *(const bf16x8*)(Bs + row * 128 + cb);
      }
#pragma unroll
      for (int mf = 0; mf < 4; ++mf)
#pragma unroll
        for (int nf = 0; nf < 4; ++nf) acc[mf][nf] = mfma16(a[mf], b[nf], acc[mf][nf]);
    }
    cur ^= 1;
  }
#pragma unroll
  for (int mf = 0; mf < 4; ++mf) {
    int row0 = tm * 128 + wm * 64 + mf * 16 + ((lane >> 4) << 2);
#pragma unroll
    for (int nf = 0; nf < 4; ++nf) {
      int col = tn * 128 + wn * 64 + nf * 16 + (lane & 15);
#pragma unroll
      for (int r = 0; r < 4; ++r)
        C[(size_t)(row0 + r) * N + col] = acc[mf][nf][r];
    }
  }
}

// ---------------------------------------------------------------------------
// Causal GQA flash attention (R8/R10 structure): dual-tile waves, swapped
// QK^T, in-register P, PV via K=32 MFMA through a kv-permuted K tile,
// KVBLK=32, fully resident (2048 x 128thr x 16KB = 8 blocks/CU, balanced).
// R11 delta: l computed BY THE MATRIX PIPE -- PV of P against an all-ones
// B-fragment accumulates l[q] in the exact acc row layout (no VALU row-sums,
// no epilogue l-shuffles, l exactly consistent with the bf16 P used in PV).
// Row-max tree grouped 3-ary for v_max3.
__global__ __launch_bounds__(128, 4) void attn(const u16* __restrict__ Q,
                                               const u16* __restrict__ Kt,
                                               const u16* __restrict__ Vt,
                                               u16* __restrict__ O) {
  __shared__ __align__(16) char smem[16384];  // per buf: K 4KB + V 4KB

  const int tid = threadIdx.x, lane = tid & 63, w = tid >> 6;  // w in {0,1}
  const int q15 = lane & 15, g = lane >> 4;
  const int bx = blockIdx.x, h = blockIdx.y, b = blockIdx.z;
  const int kh = h >> 2;
  const int QT0 = 63 - bx, QT1 = bx;  // heavy, light q-tiles (32 rows each)

  const char* Qg = (const char*)(Q + ((size_t)(b * 32 + h) * 2048) * 64);
  const char* Kg = (const char*)(Kt + ((size_t)(b * 8 + kh) * 2048 * 64));
  const char* Vg = (const char*)(Vt + ((size_t)(b * 8 + kh) * 64 * 2048));

  u32x4 onesW;
  onesW.x = onesW.y = onesW.z = onesW.w = 0x3F803F80u;  // bf16 1.0 x8
  const bf16x8 ONES = __builtin_bit_cast(bf16x8, onesW);

  // Q fragments (B-operand of swapped QK^T), both tiles
  bf16x8 qf0[2], qf1[2];
#pragma unroll
  for (int ks = 0; ks < 2; ++ks) {
    int r0 = QT0 * 32 + w * 16 + q15;
    int r1 = QT1 * 32 + w * 16 + q15;
    qf0[ks] = *(const bf16x8*)(Qg + (size_t)r0 * 128 + ks * 64 + (g << 4));
    qf1[ks] = *(const bf16x8*)(Qg + (size_t)r1 * 128 + ks * 64 + (g << 4));
  }

  f32x4 acc0[4], acc1[4], accl0, accl1;
#pragma unroll
  for (int j = 0; j < 4; ++j) {
    acc0[j] = (f32x4){0.f, 0.f, 0.f, 0.f};
    acc1[j] = (f32x4){0.f, 0.f, 0.f, 0.f};
  }
  accl0 = (f32x4){0.f, 0.f, 0.f, 0.f};
  accl1 = (f32x4){0.f, 0.f, 0.f, 0.f};
  float m0 = -1e30f, m1 = -1e30f;
  const f32x4 FZ = (f32x4){0.f, 0.f, 0.f, 0.f};

  auto stageKV = [&](int buf, int kt) {
#pragma unroll
    for (int i = 0; i < 2; ++i) {
      int vt = i * 128 + tid;  // 0..255
      // K: LDS row rho holds global kv row kappa(rho) = 8g'+4nf'+r'
      int rho = vt >> 3, ck = vt & 7;
      int kap = ((rho & 12) << 1) + ((rho & 16) >> 2) + (rho & 3);
      gload16(Kg + (size_t)(kt * 32 + kap) * 128 + (((ck ^ rho) & 7) << 4),
              smem + buf * 8192 + vt * 16);
      // V: natural kv order, 64 d-rows x 64B, chunk swizzle ^((d>>1)&3)
      int d = vt >> 2, cv = vt & 3;
      gload16(Vg + (size_t)d * 4096 + kt * 64 + (((cv ^ (d >> 1)) & 3) << 4),
              smem + buf * 8192 + 4096 + vt * 16);
    }
  };

  stageKV(0, 0);
  int cur = 0;
  const int nkt = QT0 + 1;
  for (int kt = 0; kt < nkt; ++kt) {
    __syncthreads();  // KV[cur] staged (compiler drains vmcnt before barrier)
    if (kt + 1 < nkt) stageKV(cur ^ 1, kt + 1);
    const char* Ks = smem + cur * 8192;
    const char* Vs = smem + cur * 8192 + 4096;
    const bool la = (kt <= QT1);  // light tile active

    // K fragments (A-operand), shared by both tiles
    bf16x8 kf[2][2];  // [ks][nf]
#pragma unroll
    for (int ks = 0; ks < 2; ++ks)
#pragma unroll
      for (int nf = 0; nf < 2; ++nf) {
        int r = nf * 16 + q15;
        int c = (4 * ks + g) ^ (r & 7);
        kf[ks][nf] = *(const bf16x8*)(Ks + r * 128 + (c << 4));
      }

    // swapped QK^T: lane holds S[q = Qt*32+w*16+q15][k = kt*32 + 8g+4nf+r]
    f32x4 st0[2], st1[2];
    __builtin_amdgcn_s_setprio(1);
#pragma unroll
    for (int nf = 0; nf < 2; ++nf) {
      st0[nf] = mfma16(kf[0][nf], qf0[0], FZ);
      st0[nf] = mfma16(kf[1][nf], qf0[1], st0[nf]);
    }
    if (la) {
#pragma unroll
      for (int nf = 0; nf < 2; ++nf) {
        st1[nf] = mfma16(kf[0][nf], qf1[0], FZ);
        st1[nf] = mfma16(kf[1][nf], qf1[1], st1[nf]);
      }
    }
    __builtin_amdgcn_s_setprio(0);

    // causal mask on each tile's diagonal step (k = kt*32 + 8g + 4nf + r)
    if (kt == QT0) {
      int qg = QT0 * 32 + w * 16 + q15;
#pragma unroll
      for (int nf = 0; nf < 2; ++nf)
#pragma unroll
        for (int r = 0; r < 4; ++r) {
          int kg = kt * 32 + 8 * g + 4 * nf + r;
          if (kg > qg) st0[nf][r] = -1e30f;
        }
    }
    if (la && kt == QT1) {
      int qg = QT1 * 32 + w * 16 + q15;
#pragma unroll
      for (int nf = 0; nf < 2; ++nf)
#pragma unroll
        for (int r = 0; r < 4; ++r) {
          int kg = kt * 32 + 8 * g + 4 * nf + r;
          if (kg > qg) st1[nf][r] = -1e30f;
        }
    }

    // softmax (exp2 domain): zero cross-lane ops in the common path; l is
    // accumulated by the ones-column MFMA in the PV step below.
    bf16x8 pa0, pa1;
#pragma unroll
    for (int t = 0; t < 2; ++t) {
      if (t == 1 && !la) break;
      f32x4* st = (t == 0) ? st0 : st1;
      float& m_r = (t == 0) ? m0 : m1;
      f32x4* accT = (t == 0) ? acc0 : acc1;
      f32x4& acclT = (t == 0) ? accl0 : accl1;

      // per-lane max over this lane's 8 S values + m_r, 3-ary for v_max3
      float vm = fmaxf(fmaxf(fmaxf(fmaxf(st[0][0], st[0][1]), st[0][2]),
                             fmaxf(fmaxf(st[0][3], st[1][0]), st[1][1])),
                       fmaxf(fmaxf(st[1][2], st[1][3]), m_r));
      // T13 defer-rescale: __all on per-lane max == check on the global max.
      if (!__all(vm - m_r <= 8.0f)) {
        vm = fmaxf(vm, __shfl_xor(vm, 16, 64));
        vm = fmaxf(vm, __shfl_xor(vm, 32, 64));
        float cr = EXP2(m_r - vm);
        m_r = vm;
        float cra[4];
#pragma unroll
        for (int r = 0; r < 4; ++r) cra[r] = __shfl(cr, 4 * g + r, 64);
#pragma unroll
        for (int nfd = 0; nfd < 4; ++nfd)
#pragma unroll
          for (int r = 0; r < 4; ++r) accT[nfd][r] *= cra[r];
#pragma unroll
        for (int r = 0; r < 4; ++r) acclT[r] *= cra[r];
      }
      // P = exp2(S - m); pack into the K=32 A-fragment (k = 8g + 4nf + r)
      u32x4 W;
      W.x = pk2bf(EXP2(st[0][0] - m_r), EXP2(st[0][1] - m_r));
      W.y = pk2bf(EXP2(st[0][2] - m_r), EXP2(st[0][3] - m_r));
      W.z = pk2bf(EXP2(st[1][0] - m_r), EXP2(st[1][1] - m_r));
      W.w = pk2bf(EXP2(st[1][2] - m_r), EXP2(st[1][3] - m_r));
      if (t == 0) pa0 = __builtin_bit_cast(bf16x8, W);
      else pa1 = __builtin_bit_cast(bf16x8, W);
    }

    // PV via K=32 MFMA: B-frag = V^T[d = nfd*16+q15][k = kt*32 + 8g..8g+7];
    // plus one ones-column MFMA per tile to accumulate l in acc layout.
#pragma unroll
    for (int nfd = 0; nfd < 4; ++nfd) {
      int d = nfd * 16 + q15;
      int c = (g ^ (d >> 1)) & 3;
      bf16x8 vb = *(const bf16x8*)(Vs + d * 64 + (c << 4));
      __builtin_amdgcn_s_setprio(1);
      acc0[nfd] = mfma16(pa0, vb, acc0[nfd]);
      if (la) acc1[nfd] = mfma16(pa1, vb, acc1[nfd]);
      __builtin_amdgcn_s_setprio(0);
    }
    __builtin_amdgcn_s_setprio(1);
    accl0 = mfma16(pa0, ONES, accl0);
    if (la) accl1 = mfma16(pa1, ONES, accl1);
    __builtin_amdgcn_s_setprio(0);
    cur ^= 1;
  }

  // epilogue: l is already per-lane in acc row layout -- no shuffles.
#pragma unroll
  for (int t = 0; t < 2; ++t) {
    f32x4* accT = (t == 0) ? acc0 : acc1;
    f32x4 acclT = (t == 0) ? accl0 : accl1;
    int qt = (t == 0) ? QT0 : QT1;
    u16* Og = O + ((size_t)(b * 2048 + qt * 32 + w * 16) * 2048 + h * 64);
#pragma unroll
    for (int r = 0; r < 4; ++r) {
      float li = 1.f / acclT[r];
#pragma unroll
      for (int nfd = 0; nfd < 4; ++nfd)
        Og[(size_t)(4 * g + r) * 2048 + nfd * 16 + q15] = f2bf(accT[nfd][r] * li);
    }
  }
}

// ---------------------------------------------------------------------------
extern "C" void kernel_launch(void* const* d_in, const int* in_sizes, int n_in,
                              void* d_out, int out_size, void* d_ws, size_t ws_size,
                              hipStream_t stream) {
  const float* x = (const float*)d_in[0];
  const float* fc = (const float*)d_in[1];
  const float* fs = (const float*)d_in[2];
  const float* wq = (const float*)d_in[3];
  const float* wk = (const float*)d_in[4];
  const float* wv = (const float*)d_in[5];
  const float* wo = (const float*)d_in[6];
  float* out = (float*)d_out;
  char* ws = (char*)d_ws;

  // Workspace layout (64 MB):
  u16* xb    = (u16*)(ws);                 // [4096][2048] 16 MB (reused as attn O)
  u16* Qb    = (u16*)(ws + 16777216);      // [2][32][2048][64] 16 MB (roped, exp2-scaled)
  u16* Kb    = (u16*)(ws + 33554432);      // [2][8][2048][64]   4 MB (roped)
  u16* Vsl   = (u16*)(ws + 37748736);      // [4096][512]        4 MB
  u16* Vtb   = (u16*)(ws + 41943040);      // [2][8][64][2048]   4 MB
  u16* woT   = (u16*)(ws + 46137344);      // [2048][2048]       8 MB
  u16* wqkvT = (u16*)(ws + 54525952);      // [3072][2048]      12 MB
  u16* Obuf = xb;

  dim3 tb(32, 8);
  prep<<<dim3(18432), tb, 0, stream>>>(x, wq, wk, wv, wo, xb, wqkvT, woT);
  gemm_qkv<<<dim3(24, 32), dim3(256), 0, stream>>>(xb, wqkvT, fc, fs, Qb, Kb, Vsl);
  vtrans<<<dim3(64, 2, 16), tb, 0, stream>>>(Vsl, Vtb);
  attn<<<dim3(32, 32, 2), dim3(128), 0, stream>>>(Qb, Kb, Vtb, Obuf);
  gemm_bt<<<dim3(16, 32), dim3(256), 0, stream>>>(Obuf, woT, out, 4096, 2048, 2048);
}